// Round 9
// baseline (6839.482 us; speedup 1.0000x reference)
//
#include <hip/hip_runtime.h>
#include <cstddef>

#define TSTEPS 365
#define NGRID_ 2000
#define NX_ 16
#define H_ 256
#define CPB 32
#define NBLK ((NGRID_ + CPB - 1) / CPB)   // 63 blocks, 512 threads

#define WH_WORDS (64 * 8 * 64)
#define WX_WORDS (64 * 64)

typedef __attribute__((ext_vector_type(8))) short short8v;
typedef __attribute__((ext_vector_type(4))) float f32x4;
typedef unsigned int u32;

__device__ __forceinline__ unsigned short f2bf(float f) {
    unsigned int u = __float_as_uint(f);
    u += 0x7fffu + ((u >> 16) & 1u);   // RNE
    return (unsigned short)(u >> 16);
}
__device__ __forceinline__ float bf2f(unsigned short s) {
    return __uint_as_float(((unsigned int)s) << 16);
}
__device__ __forceinline__ float sigmoid_f(float v) {
    return 1.0f / (1.0f + __expf(-v));
}
__device__ __forceinline__ float tanh_f(float v) {
    return 1.0f - 2.0f / (__expf(2.0f * v) + 1.0f);
}

// ---------------------------------------------------------------------------
// Pack wh [4][256][256] and wx [4][16][256] + gate bias b[4][256] (fp32) into
// bf16 MFMA B-fragment order. wx chunk: B rows 0..15 = wx (A hi), rows 16..31
// = wx again (A lo), EXCEPT row 31 := bias (A lo slot 15 is set to 1.0 in the
// kernel -> bias enters via MFMA; x feature 15's lo residual is dropped,
// error ~5e-4, well under threshold).
// ---------------------------------------------------------------------------
__global__ __launch_bounds__(256) void pack_weights(
    const float* __restrict__ wh, const float* __restrict__ wx,
    const float* __restrict__ b, unsigned short* __restrict__ pb)
{
    int tid = blockIdx.x * 256 + threadIdx.x;
    short8v sv;
    if (tid < WH_WORDS) {
        int lane = tid & 63;
        int kt   = (tid >> 6) & 7;
        int gu   = tid >> 9;
        int g    = gu >> 4;
        int ncol = ((gu & 15) << 4) | (lane & 15);
        int kb   = kt * 32 + ((lane >> 4) << 3);
#pragma unroll
        for (int j = 0; j < 8; ++j)
            sv[j] = (short)f2bf(wh[((size_t)(g * H_ + kb + j)) * H_ + ncol]);
        *(short8v*)(pb + (size_t)tid * 8) = sv;
    } else if (tid < WH_WORDS + WX_WORDS) {
        int t2   = tid - WH_WORDS;
        int lane = t2 & 63;
        int gu   = t2 >> 6;
        int g    = gu >> 4;
        int ncol = ((gu & 15) << 4) | (lane & 15);
        int kkb  = (lane >> 4) << 3;
#pragma unroll
        for (int j = 0; j < 8; ++j) {
            int k = (kkb + j) & 15;
            float v = wx[((size_t)(g * NX_ + k)) * H_ + ncol];
            if ((lane >> 4) == 3 && j == 7) v = b[g * H_ + ncol];  // B row 31
            sv[j] = (short)f2bf(v);
        }
        *(short8v*)(pb + (size_t)tid * 8) = sv;
    }
}

// ---------------------------------------------------------------------------
// Persistent LSTM, LDS-staged weight pipeline.
// Block = 32 cells, 512 threads (8 waves). Wave w owns units [w*32,w*32+32)
// (j=0,1) x 4 gates, both cell-tiles: acc[4][2][2] = 64 VGPRs.
// Per step: 18 phases of 32 KB weight staging (16 wh half-rounds + 2 wx),
// double-buffered in LDS via global_load_lds (width 16). Each phase: issue
// next-phase loads -> ds_read_b128 current -> 16 (or 8) MFMAs ->
// __syncthreads (implied vmcnt(0) drains the stage).
// B never lives in VGPRs -> demand ~123 < 128 budget (65536/512).
// LDS 135 KB -> 1 block/CU.
// ---------------------------------------------------------------------------
__global__ __launch_bounds__(512) void lstm_mfma(
    const float* __restrict__ x,     // [T][NGRID][NX]
    const float* __restrict__ wlin,  // [H]
    const float* __restrict__ blin,  // [1]
    const unsigned short* __restrict__ pb,
    float* __restrict__ out)         // [T][NGRID]
{
    __shared__ __align__(16) unsigned short Ah[2][32][32][8];   // 32 KB
    __shared__ __align__(16) unsigned short Al[2][32][32][8];   // 32 KB
    __shared__ __align__(16) unsigned short Ax[2][4][32][8];    // 4 KB
    __shared__ __align__(16) unsigned short Bst[2][32][512];    // 64 KB
    __shared__ float Xraw[512];                                 // 2 KB
    __shared__ float red[8][32];                                // 1 KB

    const int tid = threadIdx.x;
    const int w   = tid >> 6;
    const int l   = tid & 63;
    const int lg  = l >> 4;
    const int ln  = l & 15;
    const int c0  = blockIdx.x * CPB;

    const float wl0 = wlin[w * 32 + ln];
    const float wl1 = wlin[w * 32 + 16 + ln];
    const float bl  = blin[0];

    // stage phase p (32 KB = 32 chunks of 1 KB) into Bst[p&1].
    // chunk cidx = w*4+i; LDS dest base is wave-uniform; global src per-lane.
    auto stage = [&](int p) {
#pragma unroll
        for (int i = 0; i < 4; ++i) {
            const int cidx = w * 4 + i;
            size_t off_hw;
            if (p < 16) {
                const int kt = p >> 1, gh = p & 1;
                const int gu = (gh * 2 + (cidx >> 4)) * 16 + (cidx & 15);
                off_hw = ((size_t)gu * 8 + (size_t)kt) * 512;
            } else {
                const int gu = ((p - 16) * 2 + (cidx >> 4)) * 16 + (cidx & 15);
                off_hw = (size_t)WH_WORDS * 8 + (size_t)gu * 512;
            }
            __builtin_amdgcn_global_load_lds(
                (const __attribute__((address_space(1))) u32*)(pb + off_hw + (size_t)l * 8),
                (__attribute__((address_space(3))) u32*)(&Bst[p & 1][cidx][0]),
                16, 0, 0);
        }
    };

#define MFMA_(A, B, C) C = __builtin_amdgcn_mfma_f32_16x16x32_bf16(A, B, C, 0, 0, 0)

    // ---- prologue: zero h(-1), stage x(0), stage phase 0 ----
    {
        uint4 z = make_uint4(0, 0, 0, 0);
        ((uint4*)&Ah[0][0][0][0])[tid]       = z;
        ((uint4*)&Ah[0][0][0][0])[tid + 512] = z;
        ((uint4*)&Al[0][0][0][0])[tid]       = z;
        ((uint4*)&Al[0][0][0][0])[tid + 512] = z;
    }
    {
        const int cell = tid >> 4, nx = tid & 15;
        int gc = c0 + cell;
        if (gc >= NGRID_) gc = NGRID_ - 1;
        float v = x[(size_t)gc * NX_ + nx];
        unsigned short hi = f2bf(v);
        unsigned short lo = (nx == 15) ? f2bf(1.0f) : f2bf(v - bf2f(hi));
        Ax[0][nx >> 3][cell][nx & 7]       = hi;
        Ax[0][2 + (nx >> 3)][cell][nx & 7] = lo;
    }
    stage(0);
    __syncthreads();

    f32x4 acc[4][2][2];   // [gate][j][ct]
    float cst[2][2][4];   // [j][ct][r]
#pragma unroll
    for (int j = 0; j < 2; ++j)
#pragma unroll
        for (int ct = 0; ct < 2; ++ct)
#pragma unroll
            for (int r = 0; r < 4; ++r) cst[j][ct][r] = 0.0f;

#pragma unroll 1
    for (int t = 0; t < TSTEPS; ++t) {
        const int rb = t & 1, wb = rb ^ 1;

#pragma unroll
        for (int g = 0; g < 4; ++g)
#pragma unroll
            for (int j = 0; j < 2; ++j) {
                f32x4 zz = {0.0f, 0.0f, 0.0f, 0.0f};
                acc[g][j][0] = zz;
                acc[g][j][1] = zz;
            }

#pragma unroll
        for (int kt = 0; kt < 8; ++kt) {
            // ---- phase 2kt: gates 0,1 from Bst[0] ----
            stage(2 * kt + 1);
            short8v ah0 = *(const short8v*)&Ah[rb][kt * 4 + lg][ln][0];
            short8v al0 = *(const short8v*)&Al[rb][kt * 4 + lg][ln][0];
            short8v ah1 = *(const short8v*)&Ah[rb][kt * 4 + lg][16 + ln][0];
            short8v al1 = *(const short8v*)&Al[rb][kt * 4 + lg][16 + ln][0];
            {
                short8v b00 = *(const short8v*)&Bst[0][     w * 2 + 0][l * 8];
                short8v b01 = *(const short8v*)&Bst[0][     w * 2 + 1][l * 8];
                short8v b10 = *(const short8v*)&Bst[0][16 + w * 2 + 0][l * 8];
                short8v b11 = *(const short8v*)&Bst[0][16 + w * 2 + 1][l * 8];
                MFMA_(ah0, b00, acc[0][0][0]); MFMA_(al0, b00, acc[0][0][0]);
                MFMA_(ah1, b00, acc[0][0][1]); MFMA_(al1, b00, acc[0][0][1]);
                MFMA_(ah0, b01, acc[0][1][0]); MFMA_(al0, b01, acc[0][1][0]);
                MFMA_(ah1, b01, acc[0][1][1]); MFMA_(al1, b01, acc[0][1][1]);
                MFMA_(ah0, b10, acc[1][0][0]); MFMA_(al0, b10, acc[1][0][0]);
                MFMA_(ah1, b10, acc[1][0][1]); MFMA_(al1, b10, acc[1][0][1]);
                MFMA_(ah0, b11, acc[1][1][0]); MFMA_(al0, b11, acc[1][1][0]);
                MFMA_(ah1, b11, acc[1][1][1]); MFMA_(al1, b11, acc[1][1][1]);
            }
            __syncthreads();

            // ---- phase 2kt+1: gates 2,3 from Bst[1] ----
            stage((2 * kt + 2) % 18);
            {
                short8v b20 = *(const short8v*)&Bst[1][     w * 2 + 0][l * 8];
                short8v b21 = *(const short8v*)&Bst[1][     w * 2 + 1][l * 8];
                short8v b30 = *(const short8v*)&Bst[1][16 + w * 2 + 0][l * 8];
                short8v b31 = *(const short8v*)&Bst[1][16 + w * 2 + 1][l * 8];
                MFMA_(ah0, b20, acc[2][0][0]); MFMA_(al0, b20, acc[2][0][0]);
                MFMA_(ah1, b20, acc[2][0][1]); MFMA_(al1, b20, acc[2][0][1]);
                MFMA_(ah0, b21, acc[2][1][0]); MFMA_(al0, b21, acc[2][1][0]);
                MFMA_(ah1, b21, acc[2][1][1]); MFMA_(al1, b21, acc[2][1][1]);
                MFMA_(ah0, b30, acc[3][0][0]); MFMA_(al0, b30, acc[3][0][0]);
                MFMA_(ah1, b30, acc[3][0][1]); MFMA_(al1, b30, acc[3][0][1]);
                MFMA_(ah0, b31, acc[3][1][0]); MFMA_(al0, b31, acc[3][1][0]);
                MFMA_(ah1, b31, acc[3][1][1]); MFMA_(al1, b31, acc[3][1][1]);
            }
            __syncthreads();
        }

        // ---- phase 16: x-projection gates 0,1 (Bst[0]); also stage x(t+1) raw ----
        stage(17);
        {
            const int cell = tid >> 4, nx = tid & 15;
            const int tsrc = (t + 1 < TSTEPS) ? t + 1 : TSTEPS - 1;
            int gc = c0 + cell;
            if (gc >= NGRID_) gc = NGRID_ - 1;
            __builtin_amdgcn_global_load_lds(
                (const __attribute__((address_space(1))) u32*)(x + ((size_t)tsrc * NGRID_ + gc) * NX_ + nx),
                (__attribute__((address_space(3))) u32*)(&Xraw[w * 64]),
                4, 0, 0);
        }
        short8v ax0 = *(const short8v*)&Ax[rb][lg][ln][0];
        short8v ax1 = *(const short8v*)&Ax[rb][lg][16 + ln][0];
        {
            short8v b00 = *(const short8v*)&Bst[0][     w * 2 + 0][l * 8];
            short8v b01 = *(const short8v*)&Bst[0][     w * 2 + 1][l * 8];
            short8v b10 = *(const short8v*)&Bst[0][16 + w * 2 + 0][l * 8];
            short8v b11 = *(const short8v*)&Bst[0][16 + w * 2 + 1][l * 8];
            MFMA_(ax0, b00, acc[0][0][0]); MFMA_(ax1, b00, acc[0][0][1]);
            MFMA_(ax0, b01, acc[0][1][0]); MFMA_(ax1, b01, acc[0][1][1]);
            MFMA_(ax0, b10, acc[1][0][0]); MFMA_(ax1, b10, acc[1][0][1]);
            MFMA_(ax0, b11, acc[1][1][0]); MFMA_(ax1, b11, acc[1][1][1]);
        }
        __syncthreads();

        // ---- phase 17: x-projection gates 2,3 (Bst[1]) ----
        stage(0);   // next step's phase 0 (weights are t-invariant)
        {
            short8v b20 = *(const short8v*)&Bst[1][     w * 2 + 0][l * 8];
            short8v b21 = *(const short8v*)&Bst[1][     w * 2 + 1][l * 8];
            short8v b30 = *(const short8v*)&Bst[1][16 + w * 2 + 0][l * 8];
            short8v b31 = *(const short8v*)&Bst[1][16 + w * 2 + 1][l * 8];
            MFMA_(ax0, b20, acc[2][0][0]); MFMA_(ax1, b20, acc[2][0][1]);
            MFMA_(ax0, b21, acc[2][1][0]); MFMA_(ax1, b21, acc[2][1][1]);
            MFMA_(ax0, b30, acc[3][0][0]); MFMA_(ax1, b30, acc[3][0][1]);
            MFMA_(ax0, b31, acc[3][1][0]); MFMA_(ax1, b31, acc[3][1][1]);
        }
        __syncthreads();

        // ---- gates + state + publish h(t) + x-convert + output head ----
        float pr[2][4];
#pragma unroll
        for (int ct = 0; ct < 2; ++ct)
#pragma unroll
            for (int r = 0; r < 4; ++r) pr[ct][r] = 0.0f;

#pragma unroll
        for (int j = 0; j < 2; ++j) {
            const int u = w * 32 + j * 16 + ln;
            const float wlj = (j == 0) ? wl0 : wl1;
#pragma unroll
            for (int ct = 0; ct < 2; ++ct)
#pragma unroll
                for (int r = 0; r < 4; ++r) {
                    float ig = sigmoid_f(acc[0][j][ct][r]);
                    float fg = sigmoid_f(acc[1][j][ct][r]);
                    float gt = tanh_f(acc[2][j][ct][r]);
                    float og = sigmoid_f(acc[3][j][ct][r]);
                    float c  = fmaf(fg, cst[j][ct][r], ig * gt);
                    cst[j][ct][r] = c;
                    float h = og * tanh_f(c);
                    const int cell = ct * 16 + lg * 4 + r;
                    unsigned short hi = f2bf(h);
                    Ah[wb][u >> 3][cell][u & 7] = hi;
                    Al[wb][u >> 3][cell][u & 7] = f2bf(h - bf2f(hi));
                    pr[ct][r] = fmaf(h, wlj, pr[ct][r]);
                }
        }
        {
            const int cell = tid >> 4, nx = tid & 15;
            float v = Xraw[tid];
            unsigned short hi = f2bf(v);
            unsigned short lo = (nx == 15) ? f2bf(1.0f) : f2bf(v - bf2f(hi));
            Ax[wb][nx >> 3][cell][nx & 7]       = hi;
            Ax[wb][2 + (nx >> 3)][cell][nx & 7] = lo;
        }
#pragma unroll
        for (int ct = 0; ct < 2; ++ct)
#pragma unroll
            for (int r = 0; r < 4; ++r) {
#pragma unroll
                for (int off = 1; off < 16; off <<= 1)
                    pr[ct][r] += __shfl_xor(pr[ct][r], off);
                if (ln == 0) red[w][ct * 16 + lg * 4 + r] = pr[ct][r];
            }
        __syncthreads();

        if (tid < CPB) {
            const int gc = c0 + tid;
            if (gc < NGRID_) {
                float s = bl;
#pragma unroll
                for (int w2 = 0; w2 < 8; ++w2) s += red[w2][tid];
                out[(size_t)t * NGRID_ + gc] = s;
            }
        }
    }
#undef MFMA_
}

extern "C" void kernel_launch(void* const* d_in, const int* in_sizes, int n_in,
                              void* d_out, int out_size, void* d_ws, size_t ws_size,
                              hipStream_t stream) {
    const float* x    = (const float*)d_in[0];
    const float* wx   = (const float*)d_in[1];
    const float* wh   = (const float*)d_in[2];
    const float* b    = (const float*)d_in[3];
    const float* wlin = (const float*)d_in[4];
    const float* blin = (const float*)d_in[5];
    float* out = (float*)d_out;
    unsigned short* pb = (unsigned short*)d_ws;   // 576 KB

    hipLaunchKernelGGL(pack_weights, dim3((WH_WORDS + WX_WORDS) / 256), dim3(256),
                       0, stream, wh, wx, b, pb);
    hipLaunchKernelGGL(lstm_mfma, dim3(NBLK), dim3(512), 0, stream,
                       x, wlin, blin, pb, out);
}

// Round 10
// 5119.875 us; speedup vs baseline: 1.3359x; 1.3359x over previous
//
#include <hip/hip_runtime.h>
#include <cstddef>

#define TSTEPS 365
#define NGRID_ 2000
#define NX_ 16
#define H_ 256
#define CPB 32
#define NBLK ((NGRID_ + CPB - 1) / CPB)   // 63 blocks, 512 threads

#define WH_WORDS (64 * 8 * 64)
#define WX_WORDS (64 * 64)

typedef __attribute__((ext_vector_type(8))) short short8v;
typedef __attribute__((ext_vector_type(4))) float f32x4;
typedef unsigned int u32;

__device__ __forceinline__ unsigned short f2bf(float f) {
    unsigned int u = __float_as_uint(f);
    u += 0x7fffu + ((u >> 16) & 1u);   // RNE
    return (unsigned short)(u >> 16);
}
__device__ __forceinline__ float bf2f(unsigned short s) {
    return __uint_as_float(((unsigned int)s) << 16);
}
__device__ __forceinline__ float sigmoid_f(float v) {
    return 1.0f / (1.0f + __expf(-v));
}
__device__ __forceinline__ float tanh_f(float v) {
    return 1.0f - 2.0f / (__expf(2.0f * v) + 1.0f);
}

// ---------------------------------------------------------------------------
// Pack wh [4][256][256] and wx [4][16][256] + gate bias b[4][256] (fp32) into
// bf16 MFMA B-fragment order (identical to r9; layout validated r2-r9).
// ---------------------------------------------------------------------------
__global__ __launch_bounds__(256) void pack_weights(
    const float* __restrict__ wh, const float* __restrict__ wx,
    const float* __restrict__ b, unsigned short* __restrict__ pb)
{
    int tid = blockIdx.x * 256 + threadIdx.x;
    short8v sv;
    if (tid < WH_WORDS) {
        int lane = tid & 63;
        int kt   = (tid >> 6) & 7;
        int gu   = tid >> 9;
        int g    = gu >> 4;
        int ncol = ((gu & 15) << 4) | (lane & 15);
        int kb   = kt * 32 + ((lane >> 4) << 3);
#pragma unroll
        for (int j = 0; j < 8; ++j)
            sv[j] = (short)f2bf(wh[((size_t)(g * H_ + kb + j)) * H_ + ncol]);
        *(short8v*)(pb + (size_t)tid * 8) = sv;
    } else if (tid < WH_WORDS + WX_WORDS) {
        int t2   = tid - WH_WORDS;
        int lane = t2 & 63;
        int gu   = t2 >> 6;
        int g    = gu >> 4;
        int ncol = ((gu & 15) << 4) | (lane & 15);
        int kkb  = (lane >> 4) << 3;
#pragma unroll
        for (int j = 0; j < 8; ++j) {
            int k = (kkb + j) & 15;
            float v = wx[((size_t)(g * NX_ + k)) * H_ + ncol];
            if ((lane >> 4) == 3 && j == 7) v = b[g * H_ + ncol];  // B row 31
            sv[j] = (short)f2bf(v);
        }
        *(short8v*)(pb + (size_t)tid * 8) = sv;
    }
}

// ---------------------------------------------------------------------------
// Persistent LSTM, self-synchronized weight pipeline (ONE barrier per step).
//
// r9 post-mortem: total time = 365 x single-block step latency (block-count
// invariant); r9's 19 __syncthreads/step each drained vmcnt(0) -> ~19us/step
// of exposed L2 latency. Fix:
//  - B-chunks are WAVE-PRIVATE: wave w stages exactly the 4 chunks
//    {2w,2w+1,16+2w,17+2w} it reads -> no cross-wave sync for weights.
//  - per phase: issue next-phase loads, then counted `s_waitcnt vmcnt(4)`
//    (own prior loads done, next 4 stay in flight). No barrier.
//  - shared state (Ah/Al/Ax/red, all double-buffered) is protected by ONE
//    raw s_barrier per step with lgkmcnt(0)-only drain -> weight loads
//    stay in flight across it (T4).
// ---------------------------------------------------------------------------
__global__ __launch_bounds__(512) void lstm_mfma(
    const float* __restrict__ x,     // [T][NGRID][NX]
    const float* __restrict__ wlin,  // [H]
    const float* __restrict__ blin,  // [1]
    const unsigned short* __restrict__ pb,
    float* __restrict__ out)         // [T][NGRID]
{
    __shared__ __align__(16) unsigned short Ah[2][32][32][8];   // 32 KB
    __shared__ __align__(16) unsigned short Al[2][32][32][8];   // 32 KB
    __shared__ __align__(16) unsigned short Ax[2][4][32][8];    // 4 KB
    __shared__ __align__(16) unsigned short Bst[2][32][512];    // 64 KB
    __shared__ float Xraw[512];                                 // 2 KB
    __shared__ float red[2][8][32];                             // 2 KB

    const int tid = threadIdx.x;
    const int w   = tid >> 6;
    const int l   = tid & 63;
    const int lg  = l >> 4;
    const int ln  = l & 15;
    const int c0  = blockIdx.x * CPB;

    const float wl0 = wlin[w * 32 + ln];
    const float wl1 = wlin[w * 32 + 16 + ln];
    const float bl  = blin[0];

    // stage phase p: this wave's 4 private chunks into Bst[p&1].
    auto stage = [&](int p) {
#pragma unroll
        for (int i = 0; i < 4; ++i) {
            const int cidx = (i < 2) ? (w * 2 + i) : (14 + w * 2 + i); // 2w,2w+1,16+2w,17+2w
            size_t off_hw;
            if (p < 16) {
                const int kt = p >> 1, gh = p & 1;
                const int gu = (gh * 2 + (cidx >> 4)) * 16 + (cidx & 15);
                off_hw = ((size_t)gu * 8 + (size_t)kt) * 512;
            } else {
                const int gu = ((p - 16) * 2 + (cidx >> 4)) * 16 + (cidx & 15);
                off_hw = (size_t)WH_WORDS * 8 + (size_t)gu * 512;
            }
            __builtin_amdgcn_global_load_lds(
                (const __attribute__((address_space(1))) u32*)(pb + off_hw + (size_t)l * 8),
                (__attribute__((address_space(3))) u32*)(&Bst[p & 1][cidx][0]),
                16, 0, 0);
        }
    };

#define MFMA_(A, B, C) C = __builtin_amdgcn_mfma_f32_16x16x32_bf16(A, B, C, 0, 0, 0)
#define WAITV(N)                                                \
    do {                                                        \
        asm volatile("s_waitcnt vmcnt(" #N ")" ::: "memory");   \
        __builtin_amdgcn_sched_barrier(0);                      \
    } while (0)

    // ---- prologue: zero h(-1), stage x(0) directly, stage phase 0 ----
    {
        uint4 z = make_uint4(0, 0, 0, 0);
        ((uint4*)&Ah[0][0][0][0])[tid]       = z;
        ((uint4*)&Ah[0][0][0][0])[tid + 512] = z;
        ((uint4*)&Al[0][0][0][0])[tid]       = z;
        ((uint4*)&Al[0][0][0][0])[tid + 512] = z;
    }
    {
        const int cell = tid >> 4, nx = tid & 15;
        int gc = c0 + cell;
        if (gc >= NGRID_) gc = NGRID_ - 1;
        float v = x[(size_t)gc * NX_ + nx];
        unsigned short hi = f2bf(v);
        unsigned short lo = (nx == 15) ? f2bf(1.0f) : f2bf(v - bf2f(hi));
        Ax[0][nx >> 3][cell][nx & 7]       = hi;
        Ax[0][2 + (nx >> 3)][cell][nx & 7] = lo;
    }
    stage(0);
    __syncthreads();   // full drain once at prologue is fine

    f32x4 acc[4][2][2];   // [gate][j][ct]
    float cst[2][2][4];   // [j][ct][r]
#pragma unroll
    for (int j = 0; j < 2; ++j)
#pragma unroll
        for (int ct = 0; ct < 2; ++ct)
#pragma unroll
            for (int r = 0; r < 4; ++r) cst[j][ct][r] = 0.0f;

#pragma unroll 1
    for (int t = 0; t < TSTEPS; ++t) {
        const int rb = t & 1, wb = rb ^ 1;

#pragma unroll
        for (int g = 0; g < 4; ++g)
#pragma unroll
            for (int j = 0; j < 2; ++j) {
                f32x4 zz = {0.0f, 0.0f, 0.0f, 0.0f};
                acc[g][j][0] = zz;
                acc[g][j][1] = zz;
            }

#pragma unroll
        for (int kt = 0; kt < 8; ++kt) {
            // ---- phase 2kt: gates 0,1 from Bst[0] ----
            stage(2 * kt + 1);
            WAITV(4);
            short8v ah0 = *(const short8v*)&Ah[rb][kt * 4 + lg][ln][0];
            short8v al0 = *(const short8v*)&Al[rb][kt * 4 + lg][ln][0];
            short8v ah1 = *(const short8v*)&Ah[rb][kt * 4 + lg][16 + ln][0];
            short8v al1 = *(const short8v*)&Al[rb][kt * 4 + lg][16 + ln][0];
            {
                short8v b00 = *(const short8v*)&Bst[0][     w * 2 + 0][l * 8];
                short8v b01 = *(const short8v*)&Bst[0][     w * 2 + 1][l * 8];
                short8v b10 = *(const short8v*)&Bst[0][16 + w * 2 + 0][l * 8];
                short8v b11 = *(const short8v*)&Bst[0][16 + w * 2 + 1][l * 8];
                MFMA_(ah0, b00, acc[0][0][0]); MFMA_(al0, b00, acc[0][0][0]);
                MFMA_(ah1, b00, acc[0][0][1]); MFMA_(al1, b00, acc[0][0][1]);
                MFMA_(ah0, b01, acc[0][1][0]); MFMA_(al0, b01, acc[0][1][0]);
                MFMA_(ah1, b01, acc[0][1][1]); MFMA_(al1, b01, acc[0][1][1]);
                MFMA_(ah0, b10, acc[1][0][0]); MFMA_(al0, b10, acc[1][0][0]);
                MFMA_(ah1, b10, acc[1][0][1]); MFMA_(al1, b10, acc[1][0][1]);
                MFMA_(ah0, b11, acc[1][1][0]); MFMA_(al0, b11, acc[1][1][0]);
                MFMA_(ah1, b11, acc[1][1][1]); MFMA_(al1, b11, acc[1][1][1]);
            }

            // ---- phase 2kt+1: gates 2,3 from Bst[1] ----
            stage(2 * kt + 2 <= 17 ? 2 * kt + 2 : 0);  // kt=7 -> stage(16)
            WAITV(4);
            {
                short8v b20 = *(const short8v*)&Bst[1][     w * 2 + 0][l * 8];
                short8v b21 = *(const short8v*)&Bst[1][     w * 2 + 1][l * 8];
                short8v b30 = *(const short8v*)&Bst[1][16 + w * 2 + 0][l * 8];
                short8v b31 = *(const short8v*)&Bst[1][16 + w * 2 + 1][l * 8];
                MFMA_(ah0, b20, acc[2][0][0]); MFMA_(al0, b20, acc[2][0][0]);
                MFMA_(ah1, b20, acc[2][0][1]); MFMA_(al1, b20, acc[2][0][1]);
                MFMA_(ah0, b21, acc[2][1][0]); MFMA_(al0, b21, acc[2][1][0]);
                MFMA_(ah1, b21, acc[2][1][1]); MFMA_(al1, b21, acc[2][1][1]);
                MFMA_(ah0, b30, acc[3][0][0]); MFMA_(al0, b30, acc[3][0][0]);
                MFMA_(ah1, b30, acc[3][0][1]); MFMA_(al1, b30, acc[3][0][1]);
                MFMA_(ah0, b31, acc[3][1][0]); MFMA_(al0, b31, acc[3][1][0]);
                MFMA_(ah1, b31, acc[3][1][1]); MFMA_(al1, b31, acc[3][1][1]);
            }
        }

        // ---- phase 16: x-projection gates 0,1 (Bst[0]); stage(17); xload ----
        stage(17);
        {
            const int cell = tid >> 4, nx = tid & 15;
            const int tsrc = (t + 1 < TSTEPS) ? t + 1 : TSTEPS - 1;
            int gc = c0 + cell;
            if (gc >= NGRID_) gc = NGRID_ - 1;
            __builtin_amdgcn_global_load_lds(
                (const __attribute__((address_space(1))) u32*)(x + ((size_t)tsrc * NGRID_ + gc) * NX_ + nx),
                (__attribute__((address_space(3))) u32*)(&Xraw[w * 64]),
                4, 0, 0);
        }
        WAITV(5);
        short8v ax0 = *(const short8v*)&Ax[rb][lg][ln][0];
        short8v ax1 = *(const short8v*)&Ax[rb][lg][16 + ln][0];
        {
            short8v b00 = *(const short8v*)&Bst[0][     w * 2 + 0][l * 8];
            short8v b01 = *(const short8v*)&Bst[0][     w * 2 + 1][l * 8];
            short8v b10 = *(const short8v*)&Bst[0][16 + w * 2 + 0][l * 8];
            short8v b11 = *(const short8v*)&Bst[0][16 + w * 2 + 1][l * 8];
            MFMA_(ax0, b00, acc[0][0][0]); MFMA_(ax1, b00, acc[0][0][1]);
            MFMA_(ax0, b01, acc[0][1][0]); MFMA_(ax1, b01, acc[0][1][1]);
            MFMA_(ax0, b10, acc[1][0][0]); MFMA_(ax1, b10, acc[1][0][1]);
            MFMA_(ax0, b11, acc[1][1][0]); MFMA_(ax1, b11, acc[1][1][1]);
        }

        // ---- phase 17: x-projection gates 2,3 (Bst[1]); stage next step p0 ----
        stage(0);
        WAITV(5);
        {
            short8v b20 = *(const short8v*)&Bst[1][     w * 2 + 0][l * 8];
            short8v b21 = *(const short8v*)&Bst[1][     w * 2 + 1][l * 8];
            short8v b30 = *(const short8v*)&Bst[1][16 + w * 2 + 0][l * 8];
            short8v b31 = *(const short8v*)&Bst[1][16 + w * 2 + 1][l * 8];
            MFMA_(ax0, b20, acc[2][0][0]); MFMA_(ax1, b20, acc[2][0][1]);
            MFMA_(ax0, b21, acc[2][1][0]); MFMA_(ax1, b21, acc[2][1][1]);
            MFMA_(ax0, b30, acc[3][0][0]); MFMA_(ax1, b30, acc[3][0][1]);
            MFMA_(ax0, b31, acc[3][1][0]); MFMA_(ax1, b31, acc[3][1][1]);
        }

        // ---- gates + state + publish h(t) + output partials ----
        float pr[2][4];
#pragma unroll
        for (int ct = 0; ct < 2; ++ct)
#pragma unroll
            for (int r = 0; r < 4; ++r) pr[ct][r] = 0.0f;

#pragma unroll
        for (int j = 0; j < 2; ++j) {
            const int u = w * 32 + j * 16 + ln;
            const float wlj = (j == 0) ? wl0 : wl1;
#pragma unroll
            for (int ct = 0; ct < 2; ++ct)
#pragma unroll
                for (int r = 0; r < 4; ++r) {
                    float ig = sigmoid_f(acc[0][j][ct][r]);
                    float fg = sigmoid_f(acc[1][j][ct][r]);
                    float gt = tanh_f(acc[2][j][ct][r]);
                    float og = sigmoid_f(acc[3][j][ct][r]);
                    float c  = fmaf(fg, cst[j][ct][r], ig * gt);
                    cst[j][ct][r] = c;
                    float h = og * tanh_f(c);
                    const int cell = ct * 16 + lg * 4 + r;
                    unsigned short hi = f2bf(h);
                    Ah[wb][u >> 3][cell][u & 7] = hi;
                    Al[wb][u >> 3][cell][u & 7] = f2bf(h - bf2f(hi));
                    pr[ct][r] = fmaf(h, wlj, pr[ct][r]);
                }
        }
#pragma unroll
        for (int ct = 0; ct < 2; ++ct)
#pragma unroll
            for (int r = 0; r < 4; ++r) {
#pragma unroll
                for (int off = 1; off < 16; off <<= 1)
                    pr[ct][r] += __shfl_xor(pr[ct][r], off);
                if (ln == 0) red[rb][w][ct * 16 + lg * 4 + r] = pr[ct][r];
            }

        // x(t+1) convert (xload is older than stage(0): vmcnt(4) drains it)
        WAITV(4);
        {
            const int cell = tid >> 4, nx = tid & 15;
            float v = Xraw[tid];
            unsigned short hi = f2bf(v);
            unsigned short lo = (nx == 15) ? f2bf(1.0f) : f2bf(v - bf2f(hi));
            Ax[wb][nx >> 3][cell][nx & 7]       = hi;
            Ax[wb][2 + (nx >> 3)][cell][nx & 7] = lo;
        }

        // ---- the ONE barrier per step: lgkm drain only, vmcnt stays hot ----
        asm volatile("s_waitcnt lgkmcnt(0)" ::: "memory");
        __builtin_amdgcn_sched_barrier(0);
        __builtin_amdgcn_s_barrier();

        if (tid < CPB) {
            const int gc = c0 + tid;
            if (gc < NGRID_) {
                float s = bl;
#pragma unroll
                for (int w2 = 0; w2 < 8; ++w2) s += red[rb][w2][tid];
                out[(size_t)t * NGRID_ + gc] = s;
            }
        }
    }
#undef MFMA_
#undef WAITV
}

extern "C" void kernel_launch(void* const* d_in, const int* in_sizes, int n_in,
                              void* d_out, int out_size, void* d_ws, size_t ws_size,
                              hipStream_t stream) {
    const float* x    = (const float*)d_in[0];
    const float* wx   = (const float*)d_in[1];
    const float* wh   = (const float*)d_in[2];
    const float* b    = (const float*)d_in[3];
    const float* wlin = (const float*)d_in[4];
    const float* blin = (const float*)d_in[5];
    float* out = (float*)d_out;
    unsigned short* pb = (unsigned short*)d_ws;   // 576 KB

    hipLaunchKernelGGL(pack_weights, dim3((WH_WORDS + WX_WORDS) / 256), dim3(256),
                       0, stream, wh, wx, b, pb);
    hipLaunchKernelGGL(lstm_mfma, dim3(NBLK), dim3(512), 0, stream,
                       x, wlin, blin, pb, out);
}